// Round 10
// baseline (186.502 us; speedup 1.0000x reference)
//
#include <hip/hip_runtime.h>
#include <hip/hip_bf16.h>
#include <math.h>

#define D_MODEL 256
#define D_CLIP 768
#define NHEAD 8
#define HEAD_DIM 32
#define Q_LEN 100
#define BB 32
#define T_LEN 1203
#define TPAD 1216
#define MQ (Q_LEN*BB)          // 3200
#define LOG2E 1.4426950408889634f

typedef __bf16 bf16_t;
typedef __bf16 bf16x8 __attribute__((ext_vector_type(8)));
typedef __bf16 bf16x4 __attribute__((ext_vector_type(4)));
typedef float f32x4 __attribute__((ext_vector_type(4)));

static __device__ __forceinline__ bf16_t to_bf16(float x) { return (bf16_t)x; }

// pack two float4 (8 consecutive fp32) into a bf16x8 fragment
static __device__ __forceinline__ bf16x8 cvt8(float4 a, float4 b) {
    bf16x8 r;
    r[0] = to_bf16(a.x); r[1] = to_bf16(a.y); r[2] = to_bf16(a.z); r[3] = to_bf16(a.w);
    r[4] = to_bf16(b.x); r[5] = to_bf16(b.y); r[6] = to_bf16(b.z); r[7] = to_bf16(b.w);
    return r;
}
static __device__ __forceinline__ bf16x8 cvt8add(float4 a, float4 b, float4 c, float4 d) {
    bf16x8 r;
    r[0] = to_bf16(a.x + c.x); r[1] = to_bf16(a.y + c.y); r[2] = to_bf16(a.z + c.z); r[3] = to_bf16(a.w + c.w);
    r[4] = to_bf16(b.x + d.x); r[5] = to_bf16(b.y + d.y); r[6] = to_bf16(b.z + d.z); r[7] = to_bf16(b.w + d.w);
    return r;
}

// ---------------- q/k/v projection GEMMs, fused input conversion (fp32 sources)
// grid: x = head (8), y = row-block: [0,50) q | [50,69) k | [69,88) v
// wave tile = 16 rows x 32 cols; A and W read as fp32, converted in-register.
__launch_bounds__(256)
__global__ void proj_kernel(const float* __restrict__ tgt, const float* __restrict__ qpos,
                            const float* __restrict__ text,
                            const float* __restrict__ Wq, const float* __restrict__ Wk,
                            const float* __restrict__ Wv,
                            const float* __restrict__ bq, const float* __restrict__ bk,
                            const float* __restrict__ bv,
                            bf16_t* __restrict__ qn, bf16_t* __restrict__ kn,
                            bf16_t* __restrict__ vT) {
    const int bid = blockIdx.y;
    int z, xt;
    if (bid < 50)      { z = 0; xt = bid; }
    else if (bid < 69) { z = 1; xt = bid - 50; }
    else               { z = 2; xt = bid - 69; }
    const int j = blockIdx.x;
    const int nbase = j * 32;
    const int M = (z == 0) ? MQ : T_LEN;
    const int K = (z == 0) ? D_MODEL : D_CLIP;
    const float* Wf = (z == 0) ? Wq : (z == 1 ? Wk : Wv);
    const float* bias = (z == 0) ? bq : (z == 1 ? bk : bv);

    const int wave = threadIdx.x >> 6;
    const int lane = threadIdx.x & 63;
    const int c16 = lane & 15;
    const int quad = lane >> 4;
    const int mbase = xt * 64 + wave * 16;

    f32x4 a0 = (f32x4){0.f, 0.f, 0.f, 0.f};
    f32x4 a1 = (f32x4){0.f, 0.f, 0.f, 0.f};

    const int arow = (mbase + c16 < M) ? (mbase + c16) : (M - 1);
    const float* Ap0 = ((z == 0) ? tgt : text) + (size_t)arow * K + quad * 8;
    const float* Ap1 = ((z == 0) ? qpos : text) + (size_t)arow * K + quad * 8;  // qpos only used z==0
    const float* W0r = Wf + (size_t)(nbase + c16) * K + quad * 8;
    const float* W1r = Wf + (size_t)(nbase + 16 + c16) * K + quad * 8;
    const int ksteps = K / 32;
    if (z == 0) {
        #pragma unroll 4
        for (int ks = 0; ks < ksteps; ks++) {
            const int o = ks * 32;
            float4 t0 = *(const float4*)(Ap0 + o), t1 = *(const float4*)(Ap0 + o + 4);
            float4 p0 = *(const float4*)(Ap1 + o), p1 = *(const float4*)(Ap1 + o + 4);
            float4 w00 = *(const float4*)(W0r + o), w01 = *(const float4*)(W0r + o + 4);
            float4 w10 = *(const float4*)(W1r + o), w11 = *(const float4*)(W1r + o + 4);
            bf16x8 af = cvt8add(t0, t1, p0, p1);
            a0 = __builtin_amdgcn_mfma_f32_16x16x32_bf16(af, cvt8(w00, w01), a0, 0, 0, 0);
            a1 = __builtin_amdgcn_mfma_f32_16x16x32_bf16(af, cvt8(w10, w11), a1, 0, 0, 0);
        }
    } else {
        #pragma unroll 4
        for (int ks = 0; ks < ksteps; ks++) {
            const int o = ks * 32;
            float4 t0 = *(const float4*)(Ap0 + o), t1 = *(const float4*)(Ap0 + o + 4);
            float4 w00 = *(const float4*)(W0r + o), w01 = *(const float4*)(W0r + o + 4);
            float4 w10 = *(const float4*)(W1r + o), w11 = *(const float4*)(W1r + o + 4);
            bf16x8 af = cvt8(t0, t1);
            a0 = __builtin_amdgcn_mfma_f32_16x16x32_bf16(af, cvt8(w00, w01), a0, 0, 0, 0);
            a1 = __builtin_amdgcn_mfma_f32_16x16x32_bf16(af, cvt8(w10, w11), a1, 0, 0, 0);
        }
    }

    float b0s = bias[nbase + c16];
    float b1s = bias[nbase + 16 + c16];
    #pragma unroll
    for (int r = 0; r < 4; r++) { a0[r] += b0s; a1[r] += b1s; }
    if (z < 2) {
        #pragma unroll
        for (int r = 0; r < 4; r++) {
            float s = a0[r] * a0[r] + a1[r] * a1[r];
            #pragma unroll
            for (int o = 1; o < 16; o <<= 1) s += __shfl_xor(s, o);
            float sc = 1.0f / fmaxf(sqrtf(s), 1e-6f);
            a0[r] *= sc; a1[r] *= sc;
        }
    }
    #pragma unroll
    for (int r = 0; r < 4; r++) {
        int m = mbase + quad * 4 + r;
        if (m >= M) continue;
        if (z == 0) {
            int q = m >> 5, b = m & 31;
            size_t base = ((size_t)(b * NHEAD + j) * Q_LEN + q) * HEAD_DIM;
            qn[base + c16] = to_bf16(a0[r]);
            qn[base + 16 + c16] = to_bf16(a1[r]);
        } else if (z == 1) {
            size_t base = ((size_t)j * T_LEN + m) * HEAD_DIM;
            kn[base + c16] = to_bf16(a0[r]);
            kn[base + 16 + c16] = to_bf16(a1[r]);
        } else {
            vT[(size_t)(j * 32 + c16) * TPAD + m] = to_bf16(a0[r]);
            vT[(size_t)(j * 32 + 16 + c16) * TPAD + m] = to_bf16(a1[r]);
        }
    }
}

// ---------------- flash attention v7: fixed-max softmax + 1-iteration load prefetch
// grid (b, h, qt), 4 waves, no barrier in loop; each wave owns pairs p, p+4, ...
__launch_bounds__(256)
__global__ void attn_kernel(const bf16_t* __restrict__ qn, const bf16_t* __restrict__ kn,
                            const bf16_t* __restrict__ vT, const float* __restrict__ oov,
                            const float* __restrict__ logit_scale,
                            bf16_t* __restrict__ attn_out) {
    const int b = blockIdx.x;
    const int h = blockIdx.y;
    const int qt = blockIdx.z;
    const int qbase = qt * 16;
    const int wave = threadIdx.x >> 6;
    const int lane = threadIdx.x & 63;
    const int c16 = lane & 15;
    const int quad = lane >> 4;

    __shared__ __align__(16) bf16_t p_lds[4][2][16][40];
    __shared__ float l_lds[4][16];
    __shared__ float o_lds[4][32][16];

    const float scl = fminf(expf(logit_scale[0]), 100.0f);
    const float alpha = (float)h * (1.0f / 7.0f);
    const float sscale = scl * (1.0f - alpha) * LOG2E;
    const float oscale = alpha * LOG2E;
    const float mfix = sscale + 20.0f * oscale;

    const int q = qbase + c16;
    const int qc = (q < Q_LEN) ? q : (Q_LEN - 1);
    bf16x8 qf = *(const bf16x8*)(qn + ((size_t)(b * NHEAD + h) * Q_LEN + qc) * HEAD_DIM + quad * 8);

    f32x4 olo = (f32x4){0.f, 0.f, 0.f, 0.f};
    f32x4 ohi = (f32x4){0.f, 0.f, 0.f, 0.f};
    float l_s = 0.0f;

    const bf16_t* knh = kn + (size_t)h * T_LEN * HEAD_DIM;
    const bf16_t* vTh = vT + (size_t)h * HEAD_DIM * TPAD;
    const float* oovr = oov + ((size_t)b * Q_LEN + qc) * T_LEN;
    const f32x4 zero = (f32x4){0.f, 0.f, 0.f, 0.f};

    // current-iteration operand registers (prefetched)
    bf16x8 kA0, kA1, kB0, kB1, vA0, vA1, vB0, vB1;
    float4 oA0, oA1, oB0, oB1;

    #define LOAD_PAIR(P, kA0_, kA1_, kB0_, kB1_, vA0_, vA1_, vB0_, vB1_, oA0_, oA1_, oB0_, oB1_) \
        { const int tb0_ = (P) * 64; const int tb1_ = tb0_ + 32;                                   \
          kA0_ = *(const bf16x8*)(knh + (size_t)(tb0_ + c16) * HEAD_DIM + quad * 8);               \
          kA1_ = *(const bf16x8*)(knh + (size_t)(tb0_ + 16 + c16) * HEAD_DIM + quad * 8);          \
          kB0_ = *(const bf16x8*)(knh + (size_t)(tb1_ + c16) * HEAD_DIM + quad * 8);               \
          kB1_ = *(const bf16x8*)(knh + (size_t)(tb1_ + 16 + c16) * HEAD_DIM + quad * 8);          \
          vA0_ = *(const bf16x8*)(vTh + (size_t)c16 * TPAD + tb0_ + quad * 8);                     \
          vA1_ = *(const bf16x8*)(vTh + (size_t)(16 + c16) * TPAD + tb0_ + quad * 8);              \
          vB0_ = *(const bf16x8*)(vTh + (size_t)c16 * TPAD + tb1_ + quad * 8);                     \
          vB1_ = *(const bf16x8*)(vTh + (size_t)(16 + c16) * TPAD + tb1_ + quad * 8);              \
          oA0_ = *(const float4*)(oovr + tb0_ + quad * 4);                                         \
          oA1_ = *(const float4*)(oovr + tb0_ + 16 + quad * 4);                                    \
          oB0_ = *(const float4*)(oovr + tb1_ + quad * 4);                                         \
          oB1_ = *(const float4*)(oovr + tb1_ + 16 + quad * 4); }

    if (wave < 18) LOAD_PAIR(wave, kA0, kA1, kB0, kB1, vA0, vA1, vB0, vB1, oA0, oA1, oB0, oB1);

    for (int p = wave; p < 18; p += 4) {
        // prefetch next pair (clamped; duplicate loads are harmless)
        const int pn = (p + 4 < 18) ? (p + 4) : 17;
        bf16x8 nkA0, nkA1, nkB0, nkB1, nvA0, nvA1, nvB0, nvB1;
        float4 noA0, noA1, noB0, noB1;
        LOAD_PAIR(pn, nkA0, nkA1, nkB0, nkB1, nvA0, nvA1, nvB0, nvB1, noA0, noA1, noB0, noB1);

        // compute with current registers
        f32x4 s00 = __builtin_amdgcn_mfma_f32_16x16x32_bf16(kA0, qf, zero, 0, 0, 0);
        f32x4 s01 = __builtin_amdgcn_mfma_f32_16x16x32_bf16(kA1, qf, zero, 0, 0, 0);
        f32x4 s10 = __builtin_amdgcn_mfma_f32_16x16x32_bf16(kB0, qf, zero, 0, 0, 0);
        f32x4 s11 = __builtin_amdgcn_mfma_f32_16x16x32_bf16(kB1, qf, zero, 0, 0, 0);
        float pa0[4], pa1[4], pb0[4], pb1[4];
        float ovA0[4] = {oA0.x, oA0.y, oA0.z, oA0.w};
        float ovA1[4] = {oA1.x, oA1.y, oA1.z, oA1.w};
        float ovB0[4] = {oB0.x, oB0.y, oB0.z, oB0.w};
        float ovB1[4] = {oB1.x, oB1.y, oB1.z, oB1.w};
        #pragma unroll
        for (int r = 0; r < 4; r++) {
            pa0[r] = exp2f(fmaf(s00[r], sscale, fmaf(ovA0[r], oscale, -mfix)));
            pa1[r] = exp2f(fmaf(s01[r], sscale, fmaf(ovA1[r], oscale, -mfix)));
            pb0[r] = exp2f(fmaf(s10[r], sscale, fmaf(ovB0[r], oscale, -mfix)));
            pb1[r] = exp2f(fmaf(s11[r], sscale, fmaf(ovB1[r], oscale, -mfix)));
        }
        l_s += ((pa0[0] + pa0[1]) + (pa0[2] + pa0[3])) + ((pa1[0] + pa1[1]) + (pa1[2] + pa1[3]))
             + ((pb0[0] + pb0[1]) + (pb0[2] + pb0[3])) + ((pb1[0] + pb1[1]) + (pb1[2] + pb1[3]));
        bf16x4 wA0 = { to_bf16(pa0[0]), to_bf16(pa0[1]), to_bf16(pa0[2]), to_bf16(pa0[3]) };
        bf16x4 wA1 = { to_bf16(pa1[0]), to_bf16(pa1[1]), to_bf16(pa1[2]), to_bf16(pa1[3]) };
        bf16x4 wB0 = { to_bf16(pb0[0]), to_bf16(pb0[1]), to_bf16(pb0[2]), to_bf16(pb0[3]) };
        bf16x4 wB1 = { to_bf16(pb1[0]), to_bf16(pb1[1]), to_bf16(pb1[2]), to_bf16(pb1[3]) };
        *(bf16x4*)&p_lds[wave][0][c16][quad * 4] = wA0;
        *(bf16x4*)&p_lds[wave][0][c16][16 + quad * 4] = wA1;
        *(bf16x4*)&p_lds[wave][1][c16][quad * 4] = wB0;
        *(bf16x4*)&p_lds[wave][1][c16][16 + quad * 4] = wB1;
        bf16x8 pf0 = *(const bf16x8*)(&p_lds[wave][0][c16][quad * 8]);
        bf16x8 pf1 = *(const bf16x8*)(&p_lds[wave][1][c16][quad * 8]);
        olo = __builtin_amdgcn_mfma_f32_16x16x32_bf16(vA0, pf0, olo, 0, 0, 0);
        ohi = __builtin_amdgcn_mfma_f32_16x16x32_bf16(vA1, pf0, ohi, 0, 0, 0);
        olo = __builtin_amdgcn_mfma_f32_16x16x32_bf16(vB0, pf1, olo, 0, 0, 0);
        ohi = __builtin_amdgcn_mfma_f32_16x16x32_bf16(vB1, pf1, ohi, 0, 0, 0);

        // rotate
        kA0 = nkA0; kA1 = nkA1; kB0 = nkB0; kB1 = nkB1;
        vA0 = nvA0; vA1 = nvA1; vB0 = nvB0; vB1 = nvB1;
        oA0 = noA0; oA1 = noA1; oB0 = noB0; oB1 = noB1;
    }
    #undef LOAD_PAIR

    // peeled tile 36 (full, tb=1152) on wave 2
    if (wave == 2) {
        const int tb = 1152;
        bf16x8 kf0 = *(const bf16x8*)(knh + (size_t)(tb + c16) * HEAD_DIM + quad * 8);
        bf16x8 kf1 = *(const bf16x8*)(knh + (size_t)(tb + 16 + c16) * HEAD_DIM + quad * 8);
        float4 oa = *(const float4*)(oovr + tb + quad * 4);
        float4 oc = *(const float4*)(oovr + tb + 16 + quad * 4);
        bf16x8 v0 = *(const bf16x8*)(vTh + (size_t)c16 * TPAD + tb + quad * 8);
        bf16x8 v1 = *(const bf16x8*)(vTh + (size_t)(16 + c16) * TPAD + tb + quad * 8);
        f32x4 s0 = __builtin_amdgcn_mfma_f32_16x16x32_bf16(kf0, qf, zero, 0, 0, 0);
        f32x4 s1 = __builtin_amdgcn_mfma_f32_16x16x32_bf16(kf1, qf, zero, 0, 0, 0);
        float ova[4] = {oa.x, oa.y, oa.z, oa.w};
        float ovc[4] = {oc.x, oc.y, oc.z, oc.w};
        float p0[4], p1[4];
        #pragma unroll
        for (int r = 0; r < 4; r++) {
            p0[r] = exp2f(fmaf(s0[r], sscale, fmaf(ova[r], oscale, -mfix)));
            p1[r] = exp2f(fmaf(s1[r], sscale, fmaf(ovc[r], oscale, -mfix)));
        }
        l_s += ((p0[0] + p0[1]) + (p0[2] + p0[3])) + ((p1[0] + p1[1]) + (p1[2] + p1[3]));
        bf16x4 w0 = { to_bf16(p0[0]), to_bf16(p0[1]), to_bf16(p0[2]), to_bf16(p0[3]) };
        bf16x4 w1 = { to_bf16(p1[0]), to_bf16(p1[1]), to_bf16(p1[2]), to_bf16(p1[3]) };
        *(bf16x4*)&p_lds[wave][0][c16][quad * 4] = w0;
        *(bf16x4*)&p_lds[wave][0][c16][16 + quad * 4] = w1;
        bf16x8 pf = *(const bf16x8*)(&p_lds[wave][0][c16][quad * 8]);
        olo = __builtin_amdgcn_mfma_f32_16x16x32_bf16(v0, pf, olo, 0, 0, 0);
        ohi = __builtin_amdgcn_mfma_f32_16x16x32_bf16(v1, pf, ohi, 0, 0, 0);
    }

    // peeled tile 37 (tail, tb=1184) on wave 3
    if (wave == 3) {
        const int tb = 1184;
        int t1c = tb + 16 + c16;
        if (t1c >= T_LEN) t1c = T_LEN - 1;
        bf16x8 kf0 = *(const bf16x8*)(knh + (size_t)(tb + c16) * HEAD_DIM + quad * 8);
        bf16x8 kf1 = *(const bf16x8*)(knh + (size_t)t1c * HEAD_DIM + quad * 8);
        bf16x8 v0 = *(const bf16x8*)(vTh + (size_t)c16 * TPAD + tb + quad * 8);
        bf16x8 v1 = *(const bf16x8*)(vTh + (size_t)(16 + c16) * TPAD + tb + quad * 8);
        f32x4 s0 = __builtin_amdgcn_mfma_f32_16x16x32_bf16(kf0, qf, zero, 0, 0, 0);
        f32x4 s1 = __builtin_amdgcn_mfma_f32_16x16x32_bf16(kf1, qf, zero, 0, 0, 0);
        float p0[4], p1[4];
        #pragma unroll
        for (int r = 0; r < 4; r++) {
            int ta = tb + quad * 4 + r;
            int tb2 = tb + 16 + quad * 4 + r;
            float ova = oovr[ta];
            p0[r] = exp2f(fmaf(s0[r], sscale, fmaf(ova, oscale, -mfix)));
            if (tb2 < T_LEN) {
                float ovc = oovr[tb2];
                p1[r] = exp2f(fmaf(s1[r], sscale, fmaf(ovc, oscale, -mfix)));
            } else {
                p1[r] = 0.0f;
            }
        }
        l_s += ((p0[0] + p0[1]) + (p0[2] + p0[3])) + ((p1[0] + p1[1]) + (p1[2] + p1[3]));
        bf16x4 w0 = { to_bf16(p0[0]), to_bf16(p0[1]), to_bf16(p0[2]), to_bf16(p0[3]) };
        bf16x4 w1 = { to_bf16(p1[0]), to_bf16(p1[1]), to_bf16(p1[2]), to_bf16(p1[3]) };
        *(bf16x4*)&p_lds[wave][0][c16][quad * 4] = w0;
        *(bf16x4*)&p_lds[wave][0][c16][16 + quad * 4] = w1;
        bf16x8 pf = *(const bf16x8*)(&p_lds[wave][0][c16][quad * 8]);
        olo = __builtin_amdgcn_mfma_f32_16x16x32_bf16(v0, pf, olo, 0, 0, 0);
        ohi = __builtin_amdgcn_mfma_f32_16x16x32_bf16(v1, pf, ohi, 0, 0, 0);
    }

    // merge 4 waves
    l_s += __shfl_xor(l_s, 16);
    l_s += __shfl_xor(l_s, 32);
    if (quad == 0) l_lds[wave][c16] = l_s;
    #pragma unroll
    for (int r = 0; r < 4; r++) {
        o_lds[wave][quad * 4 + r][c16] = olo[r];
        o_lds[wave][16 + quad * 4 + r][c16] = ohi[r];
    }
    __syncthreads();
    const int q16 = threadIdx.x & 15;
    const int dd = threadIdx.x >> 4;
    float L = l_lds[0][q16] + l_lds[1][q16] + l_lds[2][q16] + l_lds[3][q16];
    const float invL = 1.0f / L;
    const int qout = qbase + q16;
    if (qout < Q_LEN) {
        #pragma unroll
        for (int half = 0; half < 2; half++) {
            int d = half * 16 + dd;
            float O = o_lds[0][d][q16] + o_lds[1][d][q16] +
                      o_lds[2][d][q16] + o_lds[3][d][q16];
            attn_out[((size_t)qout * BB + b) * D_MODEL + h * HEAD_DIM + d] = to_bf16(O * invL);
        }
    }
}

// ---------------- Wo GEMM (fp32 Wo, converted in-register) + bias + residual + LayerNorm
__launch_bounds__(256)
__global__ void out_kernel(const bf16_t* __restrict__ attn, const float* __restrict__ Wo,
                           const float* __restrict__ bo, const float* __restrict__ tgt,
                           const float* __restrict__ ln_g, const float* __restrict__ ln_b,
                           float* __restrict__ out) {
    const int xt = blockIdx.x;               // 200 tiles of 16 rows
    const int wave = threadIdx.x >> 6;
    const int lane = threadIdx.x & 63;
    const int c16 = lane & 15;
    const int quad = lane >> 4;
    const int mbase = xt * 16;

    __shared__ float xs[16][264];

    f32x4 acc[4];
    #pragma unroll
    for (int i = 0; i < 4; i++) acc[i] = (f32x4){0.f, 0.f, 0.f, 0.f};
    const bf16_t* Ap = attn + (size_t)(mbase + c16) * D_MODEL + quad * 8;
    #pragma unroll
    for (int ks = 0; ks < 8; ks++) {
        bf16x8 af = *(const bf16x8*)(Ap + ks * 32);
        #pragma unroll
        for (int nt = 0; nt < 4; nt++) {
            int n = wave * 64 + nt * 16 + c16;
            const float* wr = Wo + (size_t)n * D_MODEL + ks * 32 + quad * 8;
            float4 w0 = *(const float4*)wr;
            float4 w1 = *(const float4*)(wr + 4);
            acc[nt] = __builtin_amdgcn_mfma_f32_16x16x32_bf16(af, cvt8(w0, w1), acc[nt], 0, 0, 0);
        }
    }
    #pragma unroll
    for (int nt = 0; nt < 4; nt++) {
        int col = wave * 64 + nt * 16 + c16;
        float bb_ = bo[col];
        #pragma unroll
        for (int r = 0; r < 4; r++) {
            int m = mbase + quad * 4 + r;
            xs[quad * 4 + r][col] = acc[nt][r] + bb_ + tgt[(size_t)m * D_MODEL + col];
        }
    }
    __syncthreads();
    const int row = threadIdx.x >> 4;
    const int seg = threadIdx.x & 15;
    float sx = 0.f, sxx = 0.f;
    #pragma unroll
    for (int i = 0; i < 16; i++) {
        float x = xs[row][seg * 16 + i];
        sx += x; sxx += x * x;
    }
    #pragma unroll
    for (int o = 1; o < 16; o <<= 1) { sx += __shfl_xor(sx, o); sxx += __shfl_xor(sxx, o); }
    float mu = sx * (1.0f / 256.0f);
    float var = sxx * (1.0f / 256.0f) - mu * mu;
    float rstd = rsqrtf(fmaxf(var, 0.0f) + 1e-5f);
    size_t obase = (size_t)(mbase + row) * D_MODEL;
    #pragma unroll
    for (int i = 0; i < 16; i++) {
        int cidx = seg * 16 + i;
        out[obase + cidx] = (xs[row][cidx] - mu) * rstd * ln_g[cidx] + ln_b[cidx];
    }
}

// ------------------------------------------------------------------- launcher
extern "C" void kernel_launch(void* const* d_in, const int* in_sizes, int n_in,
                              void* d_out, int out_size, void* d_ws, size_t ws_size,
                              hipStream_t stream) {
    const float* tgt  = (const float*)d_in[0];
    const float* text = (const float*)d_in[1];
    const float* qpos = (const float*)d_in[2];
    const float* oov  = (const float*)d_in[3];
    const float* Wq = (const float*)d_in[4];
    const float* bq = (const float*)d_in[5];
    const float* Wk = (const float*)d_in[6];
    const float* bk = (const float*)d_in[7];
    const float* Wv = (const float*)d_in[8];
    const float* bv = (const float*)d_in[9];
    const float* Wo = (const float*)d_in[10];
    const float* bo = (const float*)d_in[11];
    const float* ln_g = (const float*)d_in[12];
    const float* ln_b = (const float*)d_in[13];
    const float* lsc  = (const float*)d_in[14];

    bf16_t* wsb = (bf16_t*)d_ws;             // element offsets (bf16)
    bf16_t* qn   = wsb + 0;                  // 819200
    bf16_t* kn   = wsb + 819200;             // 307968
    bf16_t* vT   = wsb + 1127168;            // 311296
    bf16_t* attn = wsb + 1438464;            // 819200 -> end 2257664 el = 4.5 MB
    float* out   = (float*)d_out;

    proj_kernel<<<dim3(8, 88, 1), 256, 0, stream>>>(tgt, qpos, text, Wq, Wk, Wv,
                                                    bq, bk, bv, qn, kn, vT);
    attn_kernel<<<dim3(32, 8, 7), 256, 0, stream>>>(qn, kn, vT, oov, lsc, attn);
    out_kernel<<<200, 256, 0, stream>>>(attn, Wo, bo, tgt, ln_g, ln_b, out);
}

// Round 11
// 172.757 us; speedup vs baseline: 1.0796x; 1.0796x over previous
//
#include <hip/hip_runtime.h>
#include <hip/hip_bf16.h>
#include <math.h>

#define D_MODEL 256
#define D_CLIP 768
#define NHEAD 8
#define HEAD_DIM 32
#define Q_LEN 100
#define BB 32
#define T_LEN 1203
#define TPAD 1216
#define MQ (Q_LEN*BB)          // 3200
#define LOG2E 1.4426950408889634f

typedef __bf16 bf16_t;
typedef __bf16 bf16x8 __attribute__((ext_vector_type(8)));
typedef __bf16 bf16x4 __attribute__((ext_vector_type(4)));
typedef float f32x4 __attribute__((ext_vector_type(4)));

static __device__ __forceinline__ bf16_t to_bf16(float x) { return (bf16_t)x; }

// ------------- prep: qin = bf16(tgt+qpos); cast text/W* -> bf16; oov -> ws (warm L2/L3)
// vec4 ranges: [0,204800) qin | [204800,566848) conv | [566848,1529248) oov copy
__global__ void prep_kernel(const float* __restrict__ tgt, const float* __restrict__ qpos,
                            const float* __restrict__ text, const float* __restrict__ Wq,
                            const float* __restrict__ Wk, const float* __restrict__ Wv,
                            const float* __restrict__ Wo, const float* __restrict__ oov,
                            bf16_t* __restrict__ qin_bf, bf16_t* __restrict__ conv_dst,
                            float* __restrict__ oov_ws) {
    int idx = blockIdx.x * 256 + threadIdx.x;          // vec4 index
    if (idx >= 1529248) return;
    if (idx < 204800) {
        float4 a = ((const float4*)tgt)[idx];
        float4 b = ((const float4*)qpos)[idx];
        bf16x4 r = { to_bf16(a.x + b.x), to_bf16(a.y + b.y),
                     to_bf16(a.z + b.z), to_bf16(a.w + b.w) };
        *(bf16x4*)(qin_bf + (size_t)idx * 4) = r;
    } else if (idx < 566848) {
        int j = idx - 204800;
        const float4* src;
        if (j < 230976)      src = (const float4*)text + j;
        else if (j < 247360) src = (const float4*)Wq + (j - 230976);
        else if (j < 296512) src = (const float4*)Wk + (j - 247360);
        else if (j < 345664) src = (const float4*)Wv + (j - 296512);
        else                 src = (const float4*)Wo + (j - 345664);
        float4 v = *src;
        bf16x4 r = { to_bf16(v.x), to_bf16(v.y), to_bf16(v.z), to_bf16(v.w) };
        *(bf16x4*)(conv_dst + (size_t)j * 4) = r;
    } else {
        int j = idx - 566848;                          // 0..962399 (3849600 floats)
        ((float4*)oov_ws)[j] = ((const float4*)oov)[j];
    }
}

// ------------------------------------------------- q/k/v projection GEMMs (MFMA, bf16 ws inputs)
__launch_bounds__(256)
__global__ void proj_kernel(const bf16_t* __restrict__ qin_bf, const bf16_t* __restrict__ text_bf,
                            const bf16_t* __restrict__ wq, const bf16_t* __restrict__ wk,
                            const bf16_t* __restrict__ wv,
                            const float* __restrict__ bq, const float* __restrict__ bk,
                            const float* __restrict__ bv,
                            bf16_t* __restrict__ qn, bf16_t* __restrict__ kn,
                            bf16_t* __restrict__ vT) {
    const int bid = blockIdx.y;
    int z, xt;
    if (bid < 50)      { z = 0; xt = bid; }
    else if (bid < 69) { z = 1; xt = bid - 50; }
    else               { z = 2; xt = bid - 69; }
    const int j = blockIdx.x;                 // head / 32-col tile
    const int nbase = j * 32;
    const int M = (z == 0) ? MQ : T_LEN;
    const int K = (z == 0) ? D_MODEL : D_CLIP;
    const bf16_t* W = (z == 0) ? wq : (z == 1 ? wk : wv);
    const float* bias = (z == 0) ? bq : (z == 1 ? bk : bv);

    const int wave = threadIdx.x >> 6;
    const int lane = threadIdx.x & 63;
    const int c16 = lane & 15;
    const int quad = lane >> 4;
    const int mbase = xt * 64 + wave * 16;

    f32x4 a0 = (f32x4){0.f, 0.f, 0.f, 0.f};
    f32x4 a1 = (f32x4){0.f, 0.f, 0.f, 0.f};

    const int arow = (mbase + c16 < M) ? (mbase + c16) : (M - 1);
    const bf16_t* Apb = ((z == 0) ? qin_bf : text_bf) + (size_t)arow * K + quad * 8;
    const bf16_t* W0 = W + (size_t)(nbase + c16) * K + quad * 8;
    const bf16_t* W1 = W + (size_t)(nbase + 16 + c16) * K + quad * 8;
    const int ksteps = K / 32;
    #pragma unroll 4
    for (int ks = 0; ks < ksteps; ks++) {
        bf16x8 af = *(const bf16x8*)(Apb + ks * 32);
        bf16x8 b0 = *(const bf16x8*)(W0 + ks * 32);
        bf16x8 b1 = *(const bf16x8*)(W1 + ks * 32);
        a0 = __builtin_amdgcn_mfma_f32_16x16x32_bf16(af, b0, a0, 0, 0, 0);
        a1 = __builtin_amdgcn_mfma_f32_16x16x32_bf16(af, b1, a1, 0, 0, 0);
    }

    float b0s = bias[nbase + c16];
    float b1s = bias[nbase + 16 + c16];
    #pragma unroll
    for (int r = 0; r < 4; r++) { a0[r] += b0s; a1[r] += b1s; }
    if (z < 2) {
        #pragma unroll
        for (int r = 0; r < 4; r++) {
            float s = a0[r] * a0[r] + a1[r] * a1[r];
            #pragma unroll
            for (int o = 1; o < 16; o <<= 1) s += __shfl_xor(s, o);
            float sc = 1.0f / fmaxf(sqrtf(s), 1e-6f);
            a0[r] *= sc; a1[r] *= sc;
        }
    }
    #pragma unroll
    for (int r = 0; r < 4; r++) {
        int m = mbase + quad * 4 + r;
        if (m >= M) continue;
        if (z == 0) {
            int q = m >> 5, b = m & 31;
            size_t base = ((size_t)(b * NHEAD + j) * Q_LEN + q) * HEAD_DIM;
            qn[base + c16] = to_bf16(a0[r]);
            qn[base + 16 + c16] = to_bf16(a1[r]);
        } else if (z == 1) {
            size_t base = ((size_t)j * T_LEN + m) * HEAD_DIM;
            kn[base + c16] = to_bf16(a0[r]);
            kn[base + 16 + c16] = to_bf16(a1[r]);
        } else {
            vT[(size_t)(j * 32 + c16) * TPAD + m] = to_bf16(a0[r]);
            vT[(size_t)(j * 32 + 16 + c16) * TPAD + m] = to_bf16(a1[r]);
        }
    }
}

// ---------------- flash attention v8: fixed-max softmax + prefetch, oov from warm ws
// grid (qt, h, b) so blocks sharing b's oov slice dispatch adjacently.
__launch_bounds__(256)
__global__ void attn_kernel(const bf16_t* __restrict__ qn, const bf16_t* __restrict__ kn,
                            const bf16_t* __restrict__ vT, const float* __restrict__ oov,
                            const float* __restrict__ logit_scale,
                            bf16_t* __restrict__ attn_out) {
    const int qt = blockIdx.x;
    const int h = blockIdx.y;
    const int b = blockIdx.z;
    const int qbase = qt * 16;
    const int wave = threadIdx.x >> 6;
    const int lane = threadIdx.x & 63;
    const int c16 = lane & 15;
    const int quad = lane >> 4;

    __shared__ __align__(16) bf16_t p_lds[4][2][16][40];
    __shared__ float l_lds[4][16];
    __shared__ float o_lds[4][32][16];

    const float scl = fminf(expf(logit_scale[0]), 100.0f);
    const float alpha = (float)h * (1.0f / 7.0f);
    const float sscale = scl * (1.0f - alpha) * LOG2E;
    const float oscale = alpha * LOG2E;
    const float mfix = sscale + 20.0f * oscale;

    const int q = qbase + c16;
    const int qc = (q < Q_LEN) ? q : (Q_LEN - 1);
    bf16x8 qf = *(const bf16x8*)(qn + ((size_t)(b * NHEAD + h) * Q_LEN + qc) * HEAD_DIM + quad * 8);

    f32x4 olo = (f32x4){0.f, 0.f, 0.f, 0.f};
    f32x4 ohi = (f32x4){0.f, 0.f, 0.f, 0.f};
    float l_s = 0.0f;

    const bf16_t* knh = kn + (size_t)h * T_LEN * HEAD_DIM;
    const bf16_t* vTh = vT + (size_t)h * HEAD_DIM * TPAD;
    const float* oovr = oov + ((size_t)b * Q_LEN + qc) * T_LEN;
    const f32x4 zero = (f32x4){0.f, 0.f, 0.f, 0.f};

    bf16x8 kA0, kA1, kB0, kB1, vA0, vA1, vB0, vB1;
    float4 oA0, oA1, oB0, oB1;

    #define LOAD_PAIR(P, kA0_, kA1_, kB0_, kB1_, vA0_, vA1_, vB0_, vB1_, oA0_, oA1_, oB0_, oB1_) \
        { const int tb0_ = (P) * 64; const int tb1_ = tb0_ + 32;                                   \
          kA0_ = *(const bf16x8*)(knh + (size_t)(tb0_ + c16) * HEAD_DIM + quad * 8);               \
          kA1_ = *(const bf16x8*)(knh + (size_t)(tb0_ + 16 + c16) * HEAD_DIM + quad * 8);          \
          kB0_ = *(const bf16x8*)(knh + (size_t)(tb1_ + c16) * HEAD_DIM + quad * 8);               \
          kB1_ = *(const bf16x8*)(knh + (size_t)(tb1_ + 16 + c16) * HEAD_DIM + quad * 8);          \
          vA0_ = *(const bf16x8*)(vTh + (size_t)c16 * TPAD + tb0_ + quad * 8);                     \
          vA1_ = *(const bf16x8*)(vTh + (size_t)(16 + c16) * TPAD + tb0_ + quad * 8);              \
          vB0_ = *(const bf16x8*)(vTh + (size_t)c16 * TPAD + tb1_ + quad * 8);                     \
          vB1_ = *(const bf16x8*)(vTh + (size_t)(16 + c16) * TPAD + tb1_ + quad * 8);              \
          oA0_ = *(const float4*)(oovr + tb0_ + quad * 4);                                         \
          oA1_ = *(const float4*)(oovr + tb0_ + 16 + quad * 4);                                    \
          oB0_ = *(const float4*)(oovr + tb1_ + quad * 4);                                         \
          oB1_ = *(const float4*)(oovr + tb1_ + 16 + quad * 4); }

    if (wave < 18) LOAD_PAIR(wave, kA0, kA1, kB0, kB1, vA0, vA1, vB0, vB1, oA0, oA1, oB0, oB1);

    for (int p = wave; p < 18; p += 4) {
        const int pn = (p + 4 < 18) ? (p + 4) : 17;
        bf16x8 nkA0, nkA1, nkB0, nkB1, nvA0, nvA1, nvB0, nvB1;
        float4 noA0, noA1, noB0, noB1;
        LOAD_PAIR(pn, nkA0, nkA1, nkB0, nkB1, nvA0, nvA1, nvB0, nvB1, noA0, noA1, noB0, noB1);

        f32x4 s00 = __builtin_amdgcn_mfma_f32_16x16x32_bf16(kA0, qf, zero, 0, 0, 0);
        f32x4 s01 = __builtin_amdgcn_mfma_f32_16x16x32_bf16(kA1, qf, zero, 0, 0, 0);
        f32x4 s10 = __builtin_amdgcn_mfma_f32_16x16x32_bf16(kB0, qf, zero, 0, 0, 0);
        f32x4 s11 = __builtin_amdgcn_mfma_f32_16x16x32_bf16(kB1, qf, zero, 0, 0, 0);
        float pa0[4], pa1[4], pb0[4], pb1[4];
        float ovA0[4] = {oA0.x, oA0.y, oA0.z, oA0.w};
        float ovA1[4] = {oA1.x, oA1.y, oA1.z, oA1.w};
        float ovB0[4] = {oB0.x, oB0.y, oB0.z, oB0.w};
        float ovB1[4] = {oB1.x, oB1.y, oB1.z, oB1.w};
        #pragma unroll
        for (int r = 0; r < 4; r++) {
            pa0[r] = exp2f(fmaf(s00[r], sscale, fmaf(ovA0[r], oscale, -mfix)));
            pa1[r] = exp2f(fmaf(s01[r], sscale, fmaf(ovA1[r], oscale, -mfix)));
            pb0[r] = exp2f(fmaf(s10[r], sscale, fmaf(ovB0[r], oscale, -mfix)));
            pb1[r] = exp2f(fmaf(s11[r], sscale, fmaf(ovB1[r], oscale, -mfix)));
        }
        l_s += ((pa0[0] + pa0[1]) + (pa0[2] + pa0[3])) + ((pa1[0] + pa1[1]) + (pa1[2] + pa1[3]))
             + ((pb0[0] + pb0[1]) + (pb0[2] + pb0[3])) + ((pb1[0] + pb1[1]) + (pb1[2] + pb1[3]));
        bf16x4 wA0 = { to_bf16(pa0[0]), to_bf16(pa0[1]), to_bf16(pa0[2]), to_bf16(pa0[3]) };
        bf16x4 wA1 = { to_bf16(pa1[0]), to_bf16(pa1[1]), to_bf16(pa1[2]), to_bf16(pa1[3]) };
        bf16x4 wB0 = { to_bf16(pb0[0]), to_bf16(pb0[1]), to_bf16(pb0[2]), to_bf16(pb0[3]) };
        bf16x4 wB1 = { to_bf16(pb1[0]), to_bf16(pb1[1]), to_bf16(pb1[2]), to_bf16(pb1[3]) };
        *(bf16x4*)&p_lds[wave][0][c16][quad * 4] = wA0;
        *(bf16x4*)&p_lds[wave][0][c16][16 + quad * 4] = wA1;
        *(bf16x4*)&p_lds[wave][1][c16][quad * 4] = wB0;
        *(bf16x4*)&p_lds[wave][1][c16][16 + quad * 4] = wB1;
        bf16x8 pf0 = *(const bf16x8*)(&p_lds[wave][0][c16][quad * 8]);
        bf16x8 pf1 = *(const bf16x8*)(&p_lds[wave][1][c16][quad * 8]);
        olo = __builtin_amdgcn_mfma_f32_16x16x32_bf16(vA0, pf0, olo, 0, 0, 0);
        ohi = __builtin_amdgcn_mfma_f32_16x16x32_bf16(vA1, pf0, ohi, 0, 0, 0);
        olo = __builtin_amdgcn_mfma_f32_16x16x32_bf16(vB0, pf1, olo, 0, 0, 0);
        ohi = __builtin_amdgcn_mfma_f32_16x16x32_bf16(vB1, pf1, ohi, 0, 0, 0);

        kA0 = nkA0; kA1 = nkA1; kB0 = nkB0; kB1 = nkB1;
        vA0 = nvA0; vA1 = nvA1; vB0 = nvB0; vB1 = nvB1;
        oA0 = noA0; oA1 = noA1; oB0 = noB0; oB1 = noB1;
    }
    #undef LOAD_PAIR

    // peeled tile 36 (full, tb=1152) on wave 2
    if (wave == 2) {
        const int tb = 1152;
        bf16x8 kf0 = *(const bf16x8*)(knh + (size_t)(tb + c16) * HEAD_DIM + quad * 8);
        bf16x8 kf1 = *(const bf16x8*)(knh + (size_t)(tb + 16 + c16) * HEAD_DIM + quad * 8);
        float4 oa = *(const float4*)(oovr + tb + quad * 4);
        float4 oc = *(const float4*)(oovr + tb + 16 + quad * 4);
        bf16x8 v0 = *(const bf16x8*)(vTh + (size_t)c16 * TPAD + tb + quad * 8);
        bf16x8 v1 = *(const bf16x8*)(vTh + (size_t)(16 + c16) * TPAD + tb + quad * 8);
        f32x4 s0 = __builtin_amdgcn_mfma_f32_16x16x32_bf16(kf0, qf, zero, 0, 0, 0);
        f32x4 s1 = __builtin_amdgcn_mfma_f32_16x16x32_bf16(kf1, qf, zero, 0, 0, 0);
        float ova[4] = {oa.x, oa.y, oa.z, oa.w};
        float ovc[4] = {oc.x, oc.y, oc.z, oc.w};
        float p0[4], p1[4];
        #pragma unroll
        for (int r = 0; r < 4; r++) {
            p0[r] = exp2f(fmaf(s0[r], sscale, fmaf(ova[r], oscale, -mfix)));
            p1[r] = exp2f(fmaf(s1[r], sscale, fmaf(ovc[r], oscale, -mfix)));
        }
        l_s += ((p0[0] + p0[1]) + (p0[2] + p0[3])) + ((p1[0] + p1[1]) + (p1[2] + p1[3]));
        bf16x4 w0 = { to_bf16(p0[0]), to_bf16(p0[1]), to_bf16(p0[2]), to_bf16(p0[3]) };
        bf16x4 w1 = { to_bf16(p1[0]), to_bf16(p1[1]), to_bf16(p1[2]), to_bf16(p1[3]) };
        *(bf16x4*)&p_lds[wave][0][c16][quad * 4] = w0;
        *(bf16x4*)&p_lds[wave][0][c16][16 + quad * 4] = w1;
        bf16x8 pf = *(const bf16x8*)(&p_lds[wave][0][c16][quad * 8]);
        olo = __builtin_amdgcn_mfma_f32_16x16x32_bf16(v0, pf, olo, 0, 0, 0);
        ohi = __builtin_amdgcn_mfma_f32_16x16x32_bf16(v1, pf, ohi, 0, 0, 0);
    }

    // peeled tile 37 (tail, tb=1184) on wave 3
    if (wave == 3) {
        const int tb = 1184;
        int t1c = tb + 16 + c16;
        if (t1c >= T_LEN) t1c = T_LEN - 1;
        bf16x8 kf0 = *(const bf16x8*)(knh + (size_t)(tb + c16) * HEAD_DIM + quad * 8);
        bf16x8 kf1 = *(const bf16x8*)(knh + (size_t)t1c * HEAD_DIM + quad * 8);
        bf16x8 v0 = *(const bf16x8*)(vTh + (size_t)c16 * TPAD + tb + quad * 8);
        bf16x8 v1 = *(const bf16x8*)(vTh + (size_t)(16 + c16) * TPAD + tb + quad * 8);
        f32x4 s0 = __builtin_amdgcn_mfma_f32_16x16x32_bf16(kf0, qf, zero, 0, 0, 0);
        f32x4 s1 = __builtin_amdgcn_mfma_f32_16x16x32_bf16(kf1, qf, zero, 0, 0, 0);
        float p0[4], p1[4];
        #pragma unroll
        for (int r = 0; r < 4; r++) {
            int ta = tb + quad * 4 + r;
            int tb2 = tb + 16 + quad * 4 + r;
            float ova = oovr[ta];
            p0[r] = exp2f(fmaf(s0[r], sscale, fmaf(ova, oscale, -mfix)));
            if (tb2 < T_LEN) {
                float ovc = oovr[tb2];
                p1[r] = exp2f(fmaf(s1[r], sscale, fmaf(ovc, oscale, -mfix)));
            } else {
                p1[r] = 0.0f;
            }
        }
        l_s += ((p0[0] + p0[1]) + (p0[2] + p0[3])) + ((p1[0] + p1[1]) + (p1[2] + p1[3]));
        bf16x4 w0 = { to_bf16(p0[0]), to_bf16(p0[1]), to_bf16(p0[2]), to_bf16(p0[3]) };
        bf16x4 w1 = { to_bf16(p1[0]), to_bf16(p1[1]), to_bf16(p1[2]), to_bf16(p1[3]) };
        *(bf16x4*)&p_lds[wave][0][c16][quad * 4] = w0;
        *(bf16x4*)&p_lds[wave][0][c16][16 + quad * 4] = w1;
        bf16x8 pf = *(const bf16x8*)(&p_lds[wave][0][c16][quad * 8]);
        olo = __builtin_amdgcn_mfma_f32_16x16x32_bf16(v0, pf, olo, 0, 0, 0);
        ohi = __builtin_amdgcn_mfma_f32_16x16x32_bf16(v1, pf, ohi, 0, 0, 0);
    }

    // merge 4 waves
    l_s += __shfl_xor(l_s, 16);
    l_s += __shfl_xor(l_s, 32);
    if (quad == 0) l_lds[wave][c16] = l_s;
    #pragma unroll
    for (int r = 0; r < 4; r++) {
        o_lds[wave][quad * 4 + r][c16] = olo[r];
        o_lds[wave][16 + quad * 4 + r][c16] = ohi[r];
    }
    __syncthreads();
    const int q16 = threadIdx.x & 15;
    const int dd = threadIdx.x >> 4;
    float L = l_lds[0][q16] + l_lds[1][q16] + l_lds[2][q16] + l_lds[3][q16];
    const float invL = 1.0f / L;
    const int qout = qbase + q16;
    if (qout < Q_LEN) {
        #pragma unroll
        for (int half = 0; half < 2; half++) {
            int d = half * 16 + dd;
            float O = o_lds[0][d][q16] + o_lds[1][d][q16] +
                      o_lds[2][d][q16] + o_lds[3][d][q16];
            attn_out[((size_t)qout * BB + b) * D_MODEL + h * HEAD_DIM + d] = to_bf16(O * invL);
        }
    }
}

// ---------------------------------------- Wo GEMM + bias + residual + LayerNorm (fp32 out)
__launch_bounds__(256)
__global__ void out_kernel(const bf16_t* __restrict__ attn, const bf16_t* __restrict__ wo,
                           const float* __restrict__ bo, const float* __restrict__ tgt,
                           const float* __restrict__ ln_g, const float* __restrict__ ln_b,
                           float* __restrict__ out) {
    const int xt = blockIdx.x;               // 200 tiles of 16 rows
    const int wave = threadIdx.x >> 6;
    const int lane = threadIdx.x & 63;
    const int c16 = lane & 15;
    const int quad = lane >> 4;
    const int mbase = xt * 16;

    __shared__ float xs[16][264];

    f32x4 acc[4];
    #pragma unroll
    for (int i = 0; i < 4; i++) acc[i] = (f32x4){0.f, 0.f, 0.f, 0.f};
    const bf16_t* Ap = attn + (size_t)(mbase + c16) * D_MODEL + quad * 8;
    #pragma unroll
    for (int ks = 0; ks < 8; ks++) {
        bf16x8 af = *(const bf16x8*)(Ap + ks * 32);
        #pragma unroll
        for (int nt = 0; nt < 4; nt++) {
            int n = wave * 64 + nt * 16 + c16;
            bf16x8 bfr = *(const bf16x8*)(wo + (size_t)n * D_MODEL + ks * 32 + quad * 8);
            acc[nt] = __builtin_amdgcn_mfma_f32_16x16x32_bf16(af, bfr, acc[nt], 0, 0, 0);
        }
    }
    #pragma unroll
    for (int nt = 0; nt < 4; nt++) {
        int col = wave * 64 + nt * 16 + c16;
        float bb_ = bo[col];
        #pragma unroll
        for (int r = 0; r < 4; r++) {
            int m = mbase + quad * 4 + r;
            xs[quad * 4 + r][col] = acc[nt][r] + bb_ + tgt[(size_t)m * D_MODEL + col];
        }
    }
    __syncthreads();
    const int row = threadIdx.x >> 4;
    const int seg = threadIdx.x & 15;
    float sx = 0.f, sxx = 0.f;
    #pragma unroll
    for (int i = 0; i < 16; i++) {
        float x = xs[row][seg * 16 + i];
        sx += x; sxx += x * x;
    }
    #pragma unroll
    for (int o = 1; o < 16; o <<= 1) { sx += __shfl_xor(sx, o); sxx += __shfl_xor(sxx, o); }
    float mu = sx * (1.0f / 256.0f);
    float var = sxx * (1.0f / 256.0f) - mu * mu;
    float rstd = rsqrtf(fmaxf(var, 0.0f) + 1e-5f);
    size_t obase = (size_t)(mbase + row) * D_MODEL;
    #pragma unroll
    for (int i = 0; i < 16; i++) {
        int cidx = seg * 16 + i;
        out[obase + cidx] = (xs[row][cidx] - mu) * rstd * ln_g[cidx] + ln_b[cidx];
    }
}

// ------------------------------------------------------------------- launcher
extern "C" void kernel_launch(void* const* d_in, const int* in_sizes, int n_in,
                              void* d_out, int out_size, void* d_ws, size_t ws_size,
                              hipStream_t stream) {
    const float* tgt  = (const float*)d_in[0];
    const float* text = (const float*)d_in[1];
    const float* qpos = (const float*)d_in[2];
    const float* oov  = (const float*)d_in[3];
    const float* Wq = (const float*)d_in[4];
    const float* bq = (const float*)d_in[5];
    const float* Wk = (const float*)d_in[6];
    const float* bk = (const float*)d_in[7];
    const float* Wv = (const float*)d_in[8];
    const float* bv = (const float*)d_in[9];
    const float* Wo = (const float*)d_in[10];
    const float* bo = (const float*)d_in[11];
    const float* ln_g = (const float*)d_in[12];
    const float* ln_b = (const float*)d_in[13];
    const float* lsc  = (const float*)d_in[14];

    bf16_t* wsb = (bf16_t*)d_ws;             // element offsets (bf16)
    bf16_t* text_bf = wsb + 0;               // 923904
    bf16_t* wq_bf   = wsb + 923904;          // 65536
    bf16_t* wk_bf   = wsb + 989440;          // 196608
    bf16_t* wv_bf   = wsb + 1186048;         // 196608
    bf16_t* wo_bf   = wsb + 1382656;         // 65536
    bf16_t* qin_bf  = wsb + 1448192;         // 819200
    bf16_t* qn      = wsb + 2267392;         // 819200
    bf16_t* kn      = wsb + 3086592;         // 307968
    bf16_t* vT      = wsb + 3394560;         // 311296
    bf16_t* attn    = wsb + 3705856;         // 819200 -> end 4525056 el = 9050112 B
    float* oov_ws   = (float*)((char*)d_ws + 9050112);   // 3849600 floats = 15.4 MB
    float* out      = (float*)d_out;

    prep_kernel<<<5975, 256, 0, stream>>>(tgt, qpos, text, Wq, Wk, Wv, Wo, oov,
                                          qin_bf, text_bf, oov_ws);
    proj_kernel<<<dim3(8, 88, 1), 256, 0, stream>>>(qin_bf, text_bf, wq_bf, wk_bf, wv_bf,
                                                    bq, bk, bv, qn, kn, vT);
    attn_kernel<<<dim3(7, 8, 32), 256, 0, stream>>>(qn, kn, vT, oov_ws, lsc, attn);
    out_kernel<<<200, 256, 0, stream>>>(attn, wo_bf, bo, tgt, ln_g, ln_b, out);
}

// Round 12
// 158.632 us; speedup vs baseline: 1.1757x; 1.0890x over previous
//
#include <hip/hip_runtime.h>
#include <hip/hip_bf16.h>
#include <math.h>

#define D_MODEL 256
#define D_CLIP 768
#define NHEAD 8
#define HEAD_DIM 32
#define Q_LEN 100
#define BB 32
#define T_LEN 1203
#define TPAD 1216
#define MQ (Q_LEN*BB)          // 3200
#define LOG2E 1.4426950408889634f

typedef __bf16 bf16_t;
typedef __bf16 bf16x8 __attribute__((ext_vector_type(8)));
typedef __bf16 bf16x4 __attribute__((ext_vector_type(4)));
typedef float f32x4 __attribute__((ext_vector_type(4)));

static __device__ __forceinline__ bf16_t to_bf16(float x) { return (bf16_t)x; }

// ------------- prep: qin = bf16(tgt+qpos); cast text/W* -> bf16 (R9 version)
__global__ void prep_kernel(const float* __restrict__ tgt, const float* __restrict__ qpos,
                            const float* __restrict__ text, const float* __restrict__ Wq,
                            const float* __restrict__ Wk, const float* __restrict__ Wv,
                            const float* __restrict__ Wo,
                            bf16_t* __restrict__ qin_bf, bf16_t* __restrict__ conv_dst) {
    int idx = blockIdx.x * 256 + threadIdx.x;          // vec4 index
    if (idx >= 566848) return;
    float4 v;
    bf16_t* dst;
    if (idx < 204800) {
        float4 a = ((const float4*)tgt)[idx];
        float4 b = ((const float4*)qpos)[idx];
        v = make_float4(a.x + b.x, a.y + b.y, a.z + b.z, a.w + b.w);
        dst = qin_bf + idx * 4;
    } else {
        int j = idx - 204800;
        const float4* src;
        if (j < 230976)      src = (const float4*)text + j;
        else if (j < 247360) src = (const float4*)Wq + (j - 230976);
        else if (j < 296512) src = (const float4*)Wk + (j - 247360);
        else if (j < 345664) src = (const float4*)Wv + (j - 296512);
        else                 src = (const float4*)Wo + (j - 345664);
        v = *src;
        dst = conv_dst + (size_t)j * 4;
    }
    bf16x4 r = { to_bf16(v.x), to_bf16(v.y), to_bf16(v.z), to_bf16(v.w) };
    *(bf16x4*)dst = r;
}

// ------------------------------------------------- q/k/v projection GEMMs (R9 version)
__launch_bounds__(256)
__global__ void proj_kernel(const bf16_t* __restrict__ qin_bf, const bf16_t* __restrict__ text_bf,
                            const bf16_t* __restrict__ wq, const bf16_t* __restrict__ wk,
                            const bf16_t* __restrict__ wv,
                            const float* __restrict__ bq, const float* __restrict__ bk,
                            const float* __restrict__ bv,
                            bf16_t* __restrict__ qn, bf16_t* __restrict__ kn,
                            bf16_t* __restrict__ vT) {
    const int bid = blockIdx.y;
    int z, xt;
    if (bid < 50)      { z = 0; xt = bid; }
    else if (bid < 69) { z = 1; xt = bid - 50; }
    else               { z = 2; xt = bid - 69; }
    const int j = blockIdx.x;
    const int nbase = j * 32;
    const int M = (z == 0) ? MQ : T_LEN;
    const int K = (z == 0) ? D_MODEL : D_CLIP;
    const bf16_t* W = (z == 0) ? wq : (z == 1 ? wk : wv);
    const float* bias = (z == 0) ? bq : (z == 1 ? bk : bv);

    const int wave = threadIdx.x >> 6;
    const int lane = threadIdx.x & 63;
    const int c16 = lane & 15;
    const int quad = lane >> 4;
    const int mbase = xt * 64 + wave * 16;

    f32x4 a0 = (f32x4){0.f, 0.f, 0.f, 0.f};
    f32x4 a1 = (f32x4){0.f, 0.f, 0.f, 0.f};

    const int arow = (mbase + c16 < M) ? (mbase + c16) : (M - 1);
    const bf16_t* Apb = ((z == 0) ? qin_bf : text_bf) + (size_t)arow * K + quad * 8;
    const bf16_t* W0 = W + (size_t)(nbase + c16) * K + quad * 8;
    const bf16_t* W1 = W + (size_t)(nbase + 16 + c16) * K + quad * 8;
    const int ksteps = K / 32;
    #pragma unroll 4
    for (int ks = 0; ks < ksteps; ks++) {
        bf16x8 af = *(const bf16x8*)(Apb + ks * 32);
        bf16x8 b0 = *(const bf16x8*)(W0 + ks * 32);
        bf16x8 b1 = *(const bf16x8*)(W1 + ks * 32);
        a0 = __builtin_amdgcn_mfma_f32_16x16x32_bf16(af, b0, a0, 0, 0, 0);
        a1 = __builtin_amdgcn_mfma_f32_16x16x32_bf16(af, b1, a1, 0, 0, 0);
    }

    float b0s = bias[nbase + c16];
    float b1s = bias[nbase + 16 + c16];
    #pragma unroll
    for (int r = 0; r < 4; r++) { a0[r] += b0s; a1[r] += b1s; }
    if (z < 2) {
        #pragma unroll
        for (int r = 0; r < 4; r++) {
            float s = a0[r] * a0[r] + a1[r] * a1[r];
            #pragma unroll
            for (int o = 1; o < 16; o <<= 1) s += __shfl_xor(s, o);
            float sc = 1.0f / fmaxf(sqrtf(s), 1e-6f);
            a0[r] *= sc; a1[r] *= sc;
        }
    }
    #pragma unroll
    for (int r = 0; r < 4; r++) {
        int m = mbase + quad * 4 + r;
        if (m >= M) continue;
        if (z == 0) {
            int q = m >> 5, b = m & 31;
            size_t base = ((size_t)(b * NHEAD + j) * Q_LEN + q) * HEAD_DIM;
            qn[base + c16] = to_bf16(a0[r]);
            qn[base + 16 + c16] = to_bf16(a1[r]);
        } else if (z == 1) {
            size_t base = ((size_t)j * T_LEN + m) * HEAD_DIM;
            kn[base + c16] = to_bf16(a0[r]);
            kn[base + 16 + c16] = to_bf16(a1[r]);
        } else {
            vT[(size_t)(j * 32 + c16) * TPAD + m] = to_bf16(a0[r]);
            vT[(size_t)(j * 32 + 16 + c16) * TPAD + m] = to_bf16(a1[r]);
        }
    }
}

// ---------------- flash attention v9: persistent (b,h) block, K in LDS, 14 waves
// grid (b, h) = 256 blocks (1/CU); block 896 thr = 14 waves; wave: qt = w>>1, thalf = w&1.
// K_h staged once in LDS (row stride 80 B, bank-2-way-free); V/oov register-prefetched.
// Fixed-max softmax; 2-wave merge per qt through LDS aliased onto dead K region.
__launch_bounds__(896)
__global__ void attn_kernel(const bf16_t* __restrict__ qn, const bf16_t* __restrict__ kn,
                            const bf16_t* __restrict__ vT, const float* __restrict__ oov,
                            const float* __restrict__ logit_scale,
                            bf16_t* __restrict__ attn_out) {
    const int b = blockIdx.x;
    const int h = blockIdx.y;
    const int tid = threadIdx.x;
    const int w = tid >> 6;
    const int lane = tid & 63;
    const int c16 = lane & 15;
    const int quad = lane >> 4;
    const int qt = w >> 1;          // 0..6
    const int thalf = w & 1;        // 0/1
    const int qbase = qt * 16;

    __shared__ __align__(16) unsigned int k_lds[24320];      // 1216 rows x 20 dwords (80 B stride)
    __shared__ __align__(16) bf16_t p_lds[14][2][16][40];

    const float scl = fminf(expf(logit_scale[0]), 100.0f);
    const float alpha = (float)h * (1.0f / 7.0f);
    const float sscale = scl * (1.0f - alpha) * LOG2E;
    const float oscale = alpha * LOG2E;
    const float mfix = sscale + 20.0f * oscale;

    const bf16_t* knh = kn + (size_t)h * T_LEN * HEAD_DIM;
    const bf16_t* vTh = vT + (size_t)h * HEAD_DIM * TPAD;

    const int qc = (qbase + c16 < Q_LEN) ? (qbase + c16) : (Q_LEN - 1);
    bf16x8 qf = *(const bf16x8*)(qn + ((size_t)(b * NHEAD + h) * Q_LEN + qc) * HEAD_DIM + quad * 8);
    const float* oovr = oov + ((size_t)b * Q_LEN + qc) * T_LEN;
    const f32x4 zero = (f32x4){0.f, 0.f, 0.f, 0.f};

    // ---- stage K_h into LDS (1203 rows x 16 dwords -> stride-20 rows), coalesced
    {
        const unsigned int* knw = (const unsigned int*)knh;
        for (int idx = tid; idx < 19248; idx += 896)
            k_lds[(idx >> 4) * 20 + (idx & 15)] = knw[idx];
    }

    f32x4 olo = (f32x4){0.f, 0.f, 0.f, 0.f};
    f32x4 ohi = (f32x4){0.f, 0.f, 0.f, 0.f};
    float l_s = 0.0f;

    #define KFRAG(trow) (*(const bf16x8*)&k_lds[(unsigned)(trow) * 20 + quad * 4])
    #define LOADPV(P, vA0_, vA1_, vB0_, vB1_, oA0_, oA1_, oB0_, oB1_)                   \
        { const int tb0_ = (P) * 64; const int tb1_ = tb0_ + 32;                         \
          vA0_ = *(const bf16x8*)(vTh + (size_t)c16 * TPAD + tb0_ + quad * 8);           \
          vA1_ = *(const bf16x8*)(vTh + (size_t)(16 + c16) * TPAD + tb0_ + quad * 8);    \
          vB0_ = *(const bf16x8*)(vTh + (size_t)c16 * TPAD + tb1_ + quad * 8);           \
          vB1_ = *(const bf16x8*)(vTh + (size_t)(16 + c16) * TPAD + tb1_ + quad * 8);    \
          oA0_ = *(const float4*)(oovr + tb0_ + quad * 4);                               \
          oA1_ = *(const float4*)(oovr + tb0_ + 16 + quad * 4);                          \
          oB0_ = *(const float4*)(oovr + tb1_ + quad * 4);                               \
          oB1_ = *(const float4*)(oovr + tb1_ + 16 + quad * 4); }

    // prefetch first pair (issued before the barrier; global loads don't need LDS)
    bf16x8 vA0, vA1, vB0, vB1;
    float4 oA0, oA1, oB0, oB1;
    LOADPV(thalf, vA0, vA1, vB0, vB1, oA0, oA1, oB0, oB1);

    __syncthreads();    // K staged

    // main loop: pairs p = thalf, thalf+2, ... < 18  (all t < 1152+? max 1151 < 1203: no clamps)
    for (int p = thalf; p < 18; p += 2) {
        const int pn = (p + 2 < 18) ? (p + 2) : p;   // harmless dup prefetch on last trip
        bf16x8 nvA0, nvA1, nvB0, nvB1;
        float4 noA0, noA1, noB0, noB1;
        LOADPV(pn, nvA0, nvA1, nvB0, nvB1, noA0, noA1, noB0, noB1);

        const int tb0 = p * 64, tb1 = tb0 + 32;
        f32x4 s00 = __builtin_amdgcn_mfma_f32_16x16x32_bf16(KFRAG(tb0 + c16), qf, zero, 0, 0, 0);
        f32x4 s01 = __builtin_amdgcn_mfma_f32_16x16x32_bf16(KFRAG(tb0 + 16 + c16), qf, zero, 0, 0, 0);
        f32x4 s10 = __builtin_amdgcn_mfma_f32_16x16x32_bf16(KFRAG(tb1 + c16), qf, zero, 0, 0, 0);
        f32x4 s11 = __builtin_amdgcn_mfma_f32_16x16x32_bf16(KFRAG(tb1 + 16 + c16), qf, zero, 0, 0, 0);

        float pa0[4], pa1[4], pb0[4], pb1[4];
        float ovA0[4] = {oA0.x, oA0.y, oA0.z, oA0.w};
        float ovA1[4] = {oA1.x, oA1.y, oA1.z, oA1.w};
        float ovB0[4] = {oB0.x, oB0.y, oB0.z, oB0.w};
        float ovB1[4] = {oB1.x, oB1.y, oB1.z, oB1.w};
        #pragma unroll
        for (int r = 0; r < 4; r++) {
            pa0[r] = exp2f(fmaf(s00[r], sscale, fmaf(ovA0[r], oscale, -mfix)));
            pa1[r] = exp2f(fmaf(s01[r], sscale, fmaf(ovA1[r], oscale, -mfix)));
            pb0[r] = exp2f(fmaf(s10[r], sscale, fmaf(ovB0[r], oscale, -mfix)));
            pb1[r] = exp2f(fmaf(s11[r], sscale, fmaf(ovB1[r], oscale, -mfix)));
        }
        l_s += ((pa0[0] + pa0[1]) + (pa0[2] + pa0[3])) + ((pa1[0] + pa1[1]) + (pa1[2] + pa1[3]))
             + ((pb0[0] + pb0[1]) + (pb0[2] + pb0[3])) + ((pb1[0] + pb1[1]) + (pb1[2] + pb1[3]));
        bf16x4 wA0 = { to_bf16(pa0[0]), to_bf16(pa0[1]), to_bf16(pa0[2]), to_bf16(pa0[3]) };
        bf16x4 wA1 = { to_bf16(pa1[0]), to_bf16(pa1[1]), to_bf16(pa1[2]), to_bf16(pa1[3]) };
        bf16x4 wB0 = { to_bf16(pb0[0]), to_bf16(pb0[1]), to_bf16(pb0[2]), to_bf16(pb0[3]) };
        bf16x4 wB1 = { to_bf16(pb1[0]), to_bf16(pb1[1]), to_bf16(pb1[2]), to_bf16(pb1[3]) };
        *(bf16x4*)&p_lds[w][0][c16][quad * 4] = wA0;
        *(bf16x4*)&p_lds[w][0][c16][16 + quad * 4] = wA1;
        *(bf16x4*)&p_lds[w][1][c16][quad * 4] = wB0;
        *(bf16x4*)&p_lds[w][1][c16][16 + quad * 4] = wB1;
        bf16x8 pf0 = *(const bf16x8*)(&p_lds[w][0][c16][quad * 8]);
        bf16x8 pf1 = *(const bf16x8*)(&p_lds[w][1][c16][quad * 8]);
        olo = __builtin_amdgcn_mfma_f32_16x16x32_bf16(vA0, pf0, olo, 0, 0, 0);
        ohi = __builtin_amdgcn_mfma_f32_16x16x32_bf16(vA1, pf0, ohi, 0, 0, 0);
        olo = __builtin_amdgcn_mfma_f32_16x16x32_bf16(vB0, pf1, olo, 0, 0, 0);
        ohi = __builtin_amdgcn_mfma_f32_16x16x32_bf16(vB1, pf1, ohi, 0, 0, 0);

        vA0 = nvA0; vA1 = nvA1; vB0 = nvB0; vB1 = nvB1;
        oA0 = noA0; oA1 = noA1; oB0 = noB0; oB1 = noB1;
    }

    // ---- peeled pair 18 (t 1152..1215; valid < 1203) on thalf==0 waves
    if (thalf == 0) {
        // tile A: t 1152..1183 — fully valid
        {
            const int tb = 1152;
            f32x4 s0 = __builtin_amdgcn_mfma_f32_16x16x32_bf16(KFRAG(tb + c16), qf, zero, 0, 0, 0);
            f32x4 s1 = __builtin_amdgcn_mfma_f32_16x16x32_bf16(KFRAG(tb + 16 + c16), qf, zero, 0, 0, 0);
            float4 oa = *(const float4*)(oovr + tb + quad * 4);
            float4 oc = *(const float4*)(oovr + tb + 16 + quad * 4);
            bf16x8 v0 = *(const bf16x8*)(vTh + (size_t)c16 * TPAD + tb + quad * 8);
            bf16x8 v1 = *(const bf16x8*)(vTh + (size_t)(16 + c16) * TPAD + tb + quad * 8);
            float ova[4] = {oa.x, oa.y, oa.z, oa.w};
            float ovc[4] = {oc.x, oc.y, oc.z, oc.w};
            float p0[4], p1[4];
            #pragma unroll
            for (int r = 0; r < 4; r++) {
                p0[r] = exp2f(fmaf(s0[r], sscale, fmaf(ova[r], oscale, -mfix)));
                p1[r] = exp2f(fmaf(s1[r], sscale, fmaf(ovc[r], oscale, -mfix)));
            }
            l_s += ((p0[0] + p0[1]) + (p0[2] + p0[3])) + ((p1[0] + p1[1]) + (p1[2] + p1[3]));
            bf16x4 w0 = { to_bf16(p0[0]), to_bf16(p0[1]), to_bf16(p0[2]), to_bf16(p0[3]) };
            bf16x4 w1 = { to_bf16(p1[0]), to_bf16(p1[1]), to_bf16(p1[2]), to_bf16(p1[3]) };
            *(bf16x4*)&p_lds[w][0][c16][quad * 4] = w0;
            *(bf16x4*)&p_lds[w][0][c16][16 + quad * 4] = w1;
            bf16x8 pf = *(const bf16x8*)(&p_lds[w][0][c16][quad * 8]);
            olo = __builtin_amdgcn_mfma_f32_16x16x32_bf16(v0, pf, olo, 0, 0, 0);
            ohi = __builtin_amdgcn_mfma_f32_16x16x32_bf16(v1, pf, ohi, 0, 0, 0);
        }
        // tile B: t 1184..1215 — subtile B rows/oov clamped, p masked
        {
            const int tb = 1184;
            int tr1 = tb + 16 + c16;                  // 1200..1215
            if (tr1 > T_LEN - 1) tr1 = T_LEN - 1;
            f32x4 s0 = __builtin_amdgcn_mfma_f32_16x16x32_bf16(KFRAG(tb + c16), qf, zero, 0, 0, 0);
            f32x4 s1 = __builtin_amdgcn_mfma_f32_16x16x32_bf16(KFRAG(tr1), qf, zero, 0, 0, 0);
            float4 oa = *(const float4*)(oovr + tb + quad * 4);   // t <= 1199, valid
            bf16x8 v0 = *(const bf16x8*)(vTh + (size_t)c16 * TPAD + tb + quad * 8);
            bf16x8 v1 = *(const bf16x8*)(vTh + (size_t)(16 + c16) * TPAD + tb + quad * 8);
            float ova[4] = {oa.x, oa.y, oa.z, oa.w};
            float p0[4], p1[4];
            #pragma unroll
            for (int r = 0; r < 4; r++) {
                p0[r] = exp2f(fmaf(s0[r], sscale, fmaf(ova[r], oscale, -mfix)));
                int t2 = tb + 16 + quad * 4 + r;      // 1200..1215
                if (t2 < T_LEN) {
                    float ovc = oovr[t2];
                    p1[r] = exp2f(fmaf(s1[r], sscale, fmaf(ovc, oscale, -mfix)));
                } else {
                    p1[r] = 0.0f;
                }
            }
            l_s += ((p0[0] + p0[1]) + (p0[2] + p0[3])) + ((p1[0] + p1[1]) + (p1[2] + p1[3]));
            bf16x4 w0 = { to_bf16(p0[0]), to_bf16(p0[1]), to_bf16(p0[2]), to_bf16(p0[3]) };
            bf16x4 w1 = { to_bf16(p1[0]), to_bf16(p1[1]), to_bf16(p1[2]), to_bf16(p1[3]) };
            *(bf16x4*)&p_lds[w][1][c16][quad * 4] = w0;
            *(bf16x4*)&p_lds[w][1][c16][16 + quad * 4] = w1;
            bf16x8 pf = *(const bf16x8*)(&p_lds[w][1][c16][quad * 8]);
            olo = __builtin_amdgcn_mfma_f32_16x16x32_bf16(v0, pf, olo, 0, 0, 0);
            ohi = __builtin_amdgcn_mfma_f32_16x16x32_bf16(v1, pf, ohi, 0, 0, 0);
        }
    }
    #undef KFRAG
    #undef LOADPV

    // l over the 4 lane-groups sharing a q
    l_s += __shfl_xor(l_s, 16);
    l_s += __shfl_xor(l_s, 32);

    // ---- merge the 2 waves per qt through LDS aliased onto dead K region
    __syncthreads();                                   // everyone done with k_lds reads
    float* mrg = (float*)k_lds;                        // 14 x 528 floats used
    const int mb = (thalf * 7 + qt) * 528;
    if (quad == 0) mrg[mb + c16] = l_s;
    #pragma unroll
    for (int r = 0; r < 4; r++) {
        mrg[mb + 16 + (quad * 4 + r) * 16 + c16] = olo[r];
        mrg[mb + 16 + (16 + quad * 4 + r) * 16 + c16] = ohi[r];
    }
    __syncthreads();
    if (thalf == 0) {
        const int d = lane & 31;
        const int qg = lane >> 5;
        const int b0 = qt * 528, b1 = (7 + qt) * 528;
        #pragma unroll
        for (int jj = 0; jj < 8; jj++) {
            int q16 = qg * 8 + jj;
            int qo = qbase + q16;
            if (qo < Q_LEN) {
                float L = mrg[b0 + q16] + mrg[b1 + q16];
                float O = mrg[b0 + 16 + d * 16 + q16] + mrg[b1 + 16 + d * 16 + q16];
                attn_out[((size_t)qo * BB + b) * D_MODEL + h * HEAD_DIM + d] = to_bf16(O / L);
            }
        }
    }
}

// ---------------------------------------- Wo GEMM + bias + residual + LayerNorm (fp32 out)
__launch_bounds__(256)
__global__ void out_kernel(const bf16_t* __restrict__ attn, const bf16_t* __restrict__ wo,
                           const float* __restrict__ bo, const float* __restrict__ tgt,
                           const float* __restrict__ ln_g, const float* __restrict__ ln_b,
                           float* __restrict__ out) {
    const int xt = blockIdx.x;               // 200 tiles of 16 rows
    const int wave = threadIdx.x >> 6;
    const int lane = threadIdx.x & 63;
    const int c16 = lane & 15;
    const int quad = lane >> 4;
    const int mbase = xt * 16;

    __shared__ float xs[16][264];

    f32x4 acc[4];
    #pragma unroll
    for (int i = 0; i < 4; i++) acc[i] = (f32x4){0.f, 0.f, 0.f, 0.f};
    const bf16_t* Ap = attn + (size_t)(mbase + c16) * D_MODEL + quad * 8;
    #pragma unroll
    for (int ks = 0; ks < 8; ks++) {
        bf16x8 af = *(const bf16x8*)(Ap + ks * 32);
        #pragma unroll
        for (int nt = 0; nt < 4; nt++) {
            int n = wave * 64 + nt * 16 + c16;
            bf16x8 bfr = *(const bf16x8*)(wo + (size_t)n * D_MODEL + ks * 32 + quad * 8);
            acc[nt] = __builtin_amdgcn_mfma_f32_16x16x32_bf16(af, bfr, acc[nt], 0, 0, 0);
        }
    }
    #pragma unroll
    for (int nt = 0; nt < 4; nt++) {
        int col = wave * 64 + nt * 16 + c16;
        float bb_ = bo[col];
        #pragma unroll
        for (int r = 0; r < 4; r++) {
            int m = mbase + quad * 4 + r;
            xs[quad * 4 + r][col] = acc[nt][r] + bb_ + tgt[(size_t)m * D_MODEL + col];
        }
    }
    __syncthreads();
    const int row = threadIdx.x >> 4;
    const int seg = threadIdx.x & 15;
    float sx = 0.f, sxx = 0.f;
    #pragma unroll
    for (int i = 0; i < 16; i++) {
        float x = xs[row][seg * 16 + i];
        sx += x; sxx += x * x;
    }
    #pragma unroll
    for (int o = 1; o < 16; o <<= 1) { sx += __shfl_xor(sx, o); sxx += __shfl_xor(sxx, o); }
    float mu = sx * (1.0f / 256.0f);
    float var = sxx * (1.0f / 256.0f) - mu * mu;
    float rstd = rsqrtf(fmaxf(var, 0.0f) + 1e-5f);
    size_t obase = (size_t)(mbase + row) * D_MODEL;
    #pragma unroll
    for (int i = 0; i < 16; i++) {
        int cidx = seg * 16 + i;
        out[obase + cidx] = (xs[row][cidx] - mu) * rstd * ln_g[cidx] + ln_b[cidx];
    }
}

// ------------------------------------------------------------------- launcher
extern "C" void kernel_launch(void* const* d_in, const int* in_sizes, int n_in,
                              void* d_out, int out_size, void* d_ws, size_t ws_size,
                              hipStream_t stream) {
    const float* tgt  = (const float*)d_in[0];
    const float* text = (const float*)d_in[1];
    const float* qpos = (const float*)d_in[2];
    const float* oov  = (const float*)d_in[3];
    const float* Wq = (const float*)d_in[4];
    const float* bq = (const float*)d_in[5];
    const float* Wk = (const float*)d_in[6];
    const float* bk = (const float*)d_in[7];
    const float* Wv = (const float*)d_in[8];
    const float* bv = (const float*)d_in[9];
    const float* Wo = (const float*)d_in[10];
    const float* bo = (const float*)d_in[11];
    const float* ln_g = (const float*)d_in[12];
    const float* ln_b = (const float*)d_in[13];
    const float* lsc  = (const float*)d_in[14];

    bf16_t* wsb = (bf16_t*)d_ws;             // element offsets (bf16)
    bf16_t* text_bf = wsb + 0;               // 923904
    bf16_t* wq_bf   = wsb + 923904;          // 65536
    bf16_t* wk_bf   = wsb + 989440;          // 196608
    bf16_t* wv_bf   = wsb + 1186048;         // 196608
    bf16_t* wo_bf   = wsb + 1382656;         // 65536
    bf16_t* qin_bf  = wsb + 1448192;         // 819200
    bf16_t* qn      = wsb + 2267392;         // 819200
    bf16_t* kn      = wsb + 3086592;         // 307968
    bf16_t* vT      = wsb + 3394560;         // 311296
    bf16_t* attn    = wsb + 3705856;         // 819200 -> end 4525056 el = 9.05 MB
    float* out      = (float*)d_out;

    prep_kernel<<<2215, 256, 0, stream>>>(tgt, qpos, text, Wq, Wk, Wv, Wo, qin_bf, text_bf);
    proj_kernel<<<dim3(8, 88, 1), 256, 0, stream>>>(qin_bf, text_bf, wq_bf, wk_bf, wv_bf,
                                                    bq, bk, bv, qn, kn, vT);
    attn_kernel<<<dim3(32, 8), 896, 0, stream>>>(qn, kn, vT, oov, lsc, attn);
    out_kernel<<<200, 256, 0, stream>>>(attn, wo_bf, bo, tgt, ln_g, ln_b, out);
}